// Round 6
// baseline (97.400 us; speedup 1.0000x reference)
//
#include <hip/hip_runtime.h>

// Problem constants
#define B 4
#define S 8192
#define D 256
#define H 8
#define NT 128               // col-stat tiles per batch (kA), 64 rows each
#define NE 256               // kE tiles per batch, 32 rows each
#define LOG2E 1.4426950408889634f

// 6-bit involution: swaps low 3 and high 3 bits. Spreads stride-16 float4
// reads across all 8 bank-quads (2-way max), keeps linear writes clean.
#define ROT3(x) ((((x) & 7) << 3) | ((x) >> 3))

// Workspace layout (float offsets)
#define WS_WQ    0
#define WS_WV    8
#define WS_QMAX  16
#define WS_QMIN  (WS_QMAX + B*D)
#define WS_CV    (WS_QMIN + B*D)
#define WS_ZACC  (WS_CV + B*D)          // B*H*D = 8192 accumulators
#define WS_WP    (WS_ZACC + B*H*D)      // 1024 weight partials
#define WS_P1    (WS_WP + 1024)
#define WS_P2    (WS_P1 + B*NT*D)
#define WS_P3    (WS_P2 + B*NT*D)

// ---------------------------------------------------------------------------
// kA: blocks [0,512): per-tile col stats of q (max/min) and v (sum).
//     blocks [512,768): weight-chunk partial sums.
__global__ __launch_bounds__(256) void kA(const float* __restrict__ q,
                                          const float* __restrict__ v,
                                          const float* __restrict__ qw,
                                          const float* __restrict__ vw,
                                          float* __restrict__ ws) {
    const int blk = blockIdx.x;
    const int t = threadIdx.x, w = t >> 6, lane = t & 63;

    if (blk >= B * NT) {                       // weight partials
        const int i = blk - B * NT;            // 0..255: which=i>>7, h=(i>>4)&7, ch=i&15
        const float4* src = (const float4*)(((i >> 7) ? vw : qw)
                              + (size_t)((i >> 4) & 7) * D * D) + (i & 15) * 1024;
        float sm = 0.f;
        #pragma unroll
        for (int j = 0; j < 4; ++j) {
            float4 a4 = src[j * 256 + t];
            sm += (a4.x + a4.y) + (a4.z + a4.w);
        }
        #pragma unroll
        for (int off = 32; off; off >>= 1) sm += __shfl_down(sm, off, 64);
        if (lane == 0) ws[WS_WP + i * 4 + w] = sm;
        return;
    }

    const int b = blk >> 7, tl = blk & (NT - 1);
    const int g = lane >> 4, cl = lane & 15;
    const int cblk = w * 16 + cl;              // 16B col block, 0..63
    const float4* qbase = (const float4*)(q + ((size_t)b * S + tl * 64) * D);
    const float4* vbase = (const float4*)(v + ((size_t)b * S + tl * 64) * D);
    float4 qmx = make_float4(-3.4e38f, -3.4e38f, -3.4e38f, -3.4e38f);
    float4 qmn = make_float4(3.4e38f, 3.4e38f, 3.4e38f, 3.4e38f);
    float4 vs = make_float4(0.f, 0.f, 0.f, 0.f);
    #pragma unroll 4
    for (int i = 0; i < 16; ++i) {
        const int row = i * 4 + g;
        float4 a4 = qbase[row * 64 + cblk];
        qmx.x = fmaxf(qmx.x, a4.x); qmx.y = fmaxf(qmx.y, a4.y);
        qmx.z = fmaxf(qmx.z, a4.z); qmx.w = fmaxf(qmx.w, a4.w);
        qmn.x = fminf(qmn.x, a4.x); qmn.y = fminf(qmn.y, a4.y);
        qmn.z = fminf(qmn.z, a4.z); qmn.w = fminf(qmn.w, a4.w);
        float4 b4 = vbase[row * 64 + cblk];
        vs.x += b4.x; vs.y += b4.y; vs.z += b4.z; vs.w += b4.w;
    }
    #pragma unroll
    for (int off = 16; off <= 32; off <<= 1) {
        qmx.x = fmaxf(qmx.x, __shfl_xor(qmx.x, off, 64));
        qmx.y = fmaxf(qmx.y, __shfl_xor(qmx.y, off, 64));
        qmx.z = fmaxf(qmx.z, __shfl_xor(qmx.z, off, 64));
        qmx.w = fmaxf(qmx.w, __shfl_xor(qmx.w, off, 64));
        qmn.x = fminf(qmn.x, __shfl_xor(qmn.x, off, 64));
        qmn.y = fminf(qmn.y, __shfl_xor(qmn.y, off, 64));
        qmn.z = fminf(qmn.z, __shfl_xor(qmn.z, off, 64));
        qmn.w = fminf(qmn.w, __shfl_xor(qmn.w, off, 64));
        vs.x += __shfl_xor(vs.x, off, 64);
        vs.y += __shfl_xor(vs.y, off, 64);
        vs.z += __shfl_xor(vs.z, off, 64);
        vs.w += __shfl_xor(vs.w, off, 64);
    }
    if (g == 0) {
        size_t pi = (size_t)(b * NT + tl) * D + cblk * 4;
        *(float4*)&ws[WS_P1 + pi] = qmx;
        *(float4*)&ws[WS_P2 + pi] = qmn;
        *(float4*)&ws[WS_P3 + pi] = vs;
    }
}

// ---------------------------------------------------------------------------
// kB: blocks 0..31 finish col stats; block 32 finishes weight sums;
//     block 33 zeroes the Z accumulators.
__global__ __launch_bounds__(256) void kB(float* __restrict__ ws) {
    const int blk = blockIdx.x, t = threadIdx.x;
    if (blk < 32) {
        const int bb = blk >> 3, oct = blk & 7;
        const int dl = t >> 3, sub = t & 7;
        const int d = oct * 32 + dl;
        float mx = -3.4e38f, mn = 3.4e38f, sm = 0.f;
        #pragma unroll 4
        for (int i = 0; i < 16; ++i) {
            size_t idx = (size_t)(bb * NT + sub * 16 + i) * D + d;
            mx = fmaxf(mx, ws[WS_P1 + idx]);
            mn = fminf(mn, ws[WS_P2 + idx]);
            sm += ws[WS_P3 + idx];
        }
        #pragma unroll
        for (int off = 1; off < 8; off <<= 1) {
            mx = fmaxf(mx, __shfl_xor(mx, off, 64));
            mn = fminf(mn, __shfl_xor(mn, off, 64));
            sm += __shfl_xor(sm, off, 64);
        }
        if (sub == 0) {
            ws[WS_QMAX + bb * D + d] = mx;
            ws[WS_QMIN + bb * D + d] = mn;
            ws[WS_CV + bb * D + d] = sm * (float)D;
        }
    } else if (blk == 32) {
        const int o = t >> 4, j = t & 15;        // o: 0..15 = (which,h)
        float s = 0.f;
        #pragma unroll
        for (int ww = 0; ww < 4; ++ww) s += ws[WS_WP + (o * 16 + j) * 4 + ww];
        #pragma unroll
        for (int off = 1; off < 16; off <<= 1) s += __shfl_xor(s, off, 64);
        if (j == 0) ws[(o >= 8) ? (WS_WV + o - 8) : (WS_WQ + o)] = s;
    } else {
        #pragma unroll
        for (int e = 0; e < 8; ++e)
            *(float4*)&ws[WS_ZACC + e * 1024 + t * 4] = make_float4(0.f, 0.f, 0.f, 0.f);
    }
}

// ---------------------------------------------------------------------------
// kC: Z partials over 32-row chunks, accumulated with atomicAdd into WS_ZACC.
__global__ __launch_bounds__(256) void kC(const float* __restrict__ q,
                                          float* __restrict__ ws) {
    const int blk = blockIdx.x;          // 1024 blocks: b = blk>>8, chunk = blk&255
    const int b = blk >> 8, c = blk & 255;
    const int d = threadIdx.x;
    const float qmx = ws[WS_QMAX + b * D + d];
    const float qmn = ws[WS_QMIN + b * D + d];
    float a[H], cc[H], z[H];
    #pragma unroll
    for (int h = 0; h < H; ++h) {
        float wq_ = ws[WS_WQ + h];
        float M = (wq_ >= 0.f) ? wq_ * qmx : wq_ * qmn;  // max_s of wq*q[b,s,d]
        a[h] = wq_ * LOG2E;
        cc[h] = -M * LOG2E;
        z[h] = 0.f;
    }
    const float* qp = q + ((size_t)b * S + c * 32) * D + d;
    #pragma unroll 4
    for (int r = 0; r < 32; ++r) {
        float qv = qp[(size_t)r * D];
        #pragma unroll
        for (int h = 0; h < H; ++h) z[h] += exp2f(fmaf(qv, a[h], cc[h]));
    }
    #pragma unroll
    for (int h = 0; h < H; ++h)
        atomicAdd(&ws[WS_ZACC + (b * H + h) * D + d], z[h]);
}

// ---------------------------------------------------------------------------
// kE v3: 1024 blocks x 32 rows. kc in LDS with ROT3-swizzled 16B blocks
// (linear conflict-free writes, 2-way-max reads). kc re-read per head keeps
// VGPR ~90. 16-lane row slices + shfl reduce; wave-contiguous 1KB stores.
__global__ __launch_bounds__(256) void kE(const float* __restrict__ q,
                                          const float* __restrict__ ws,
                                          float* __restrict__ out) {
    __shared__ float kcs[H * D];
    const int blk = blockIdx.x;
    const int b = blk >> 8, tl = blk & (NE - 1);
    const int t = threadIdx.x, w = t >> 6, lane = t & 63;

    // prologue: kcs[h*256 + ROT3(cb)*4 + comp] = kc[h][cb*4+comp]; linear store.
    #pragma unroll
    for (int e = 0; e < 8; ++e) {
        const int p = e * 256 + t;
        const int h = p >> 8, f = p & 255;
        const int col = ROT3(f >> 2) * 4 + (f & 3);
        const float wq_ = ws[WS_WQ + h];
        const float M = (wq_ >= 0.f) ? wq_ * ws[WS_QMAX + b * D + col]
                                     : wq_ * ws[WS_QMIN + b * D + col];
        kcs[p] = -M * LOG2E - log2f(ws[WS_ZACC + (b * H + h) * D + col]);
    }
    __syncthreads();

    const int g = lane >> 4, sl = lane & 15;   // g: row in group-of-4; sl: col slice
    int r0 = ROT3(sl * 4 + 0) * 4, r1 = ROT3(sl * 4 + 1) * 4;
    int r2 = ROT3(sl * 4 + 2) * 4, r3 = ROT3(sl * 4 + 3) * 4;

    float a[H], wv_[H];
    #pragma unroll
    for (int h = 0; h < H; ++h) {
        a[h] = ws[WS_WQ + h] * LOG2E;
        wv_[h] = ws[WS_WV + h];
    }
    const float4 cvs = *(const float4*)&ws[WS_CV + b * D + lane * 4];

    const float* qrow = q + ((size_t)b * S + tl * 32 + w * 8) * D;
    float* orow = out + ((size_t)b * S + tl * 32 + w * 8) * D;

    // load both row-groups up front (rows w*8 + it*4 + g)
    const float4* qpa = (const float4*)(qrow + g * D + sl * 16);
    const float4* qpb = (const float4*)(qrow + (4 + g) * D + sl * 16);
    float4 qa0 = qpa[0], qa1 = qpa[1], qa2 = qpa[2], qa3 = qpa[3];
    float4 qb0 = qpb[0], qb1 = qpb[1], qb2 = qpb[2], qb3 = qpb[3];

    #pragma unroll
    for (int it = 0; it < 2; ++it) {
        const float4 q0 = it ? qb0 : qa0, q1 = it ? qb1 : qa1;
        const float4 q2 = it ? qb2 : qa2, q3 = it ? qb3 : qa3;
        float p[H];
        #pragma unroll
        for (int h = 0; h < H; ++h) {
            const float4 k0 = *(const float4*)&kcs[h * 256 + r0];
            const float4 k1 = *(const float4*)&kcs[h * 256 + r1];
            const float4 k2 = *(const float4*)&kcs[h * 256 + r2];
            const float4 k3 = *(const float4*)&kcs[h * 256 + r3];
            p[h] = ((exp2f(fmaf(q0.x, a[h], k0.x)) + exp2f(fmaf(q0.y, a[h], k0.y)))
                  + (exp2f(fmaf(q0.z, a[h], k0.z)) + exp2f(fmaf(q0.w, a[h], k0.w))))
                 + ((exp2f(fmaf(q1.x, a[h], k1.x)) + exp2f(fmaf(q1.y, a[h], k1.y)))
                  + (exp2f(fmaf(q1.z, a[h], k1.z)) + exp2f(fmaf(q1.w, a[h], k1.w))))
                 + ((exp2f(fmaf(q2.x, a[h], k2.x)) + exp2f(fmaf(q2.y, a[h], k2.y)))
                  + (exp2f(fmaf(q2.z, a[h], k2.z)) + exp2f(fmaf(q2.w, a[h], k2.w))))
                 + ((exp2f(fmaf(q3.x, a[h], k3.x)) + exp2f(fmaf(q3.y, a[h], k3.y)))
                  + (exp2f(fmaf(q3.z, a[h], k3.z)) + exp2f(fmaf(q3.w, a[h], k3.w))));
        }
        #pragma unroll
        for (int st = 1; st < 16; st <<= 1) {
            #pragma unroll
            for (int h = 0; h < H; ++h) p[h] += __shfl_xor(p[h], st, 16);
        }
        float amax = -3.4e38f, amin = 3.4e38f;
        #pragma unroll
        for (int h = 0; h < H; ++h) {
            float A = wv_[h] * p[h];
            amax = fmaxf(amax, A);
            amin = fminf(amin, A);
        }
        #pragma unroll
        for (int rr = 0; rr < 4; ++rr) {
            const float am = __shfl(amax, rr * 16, 64);
            const float an = __shfl(amin, rr * 16, 64);
            float4 o;
            o.x = (cvs.x >= 0.f) ? cvs.x * am : cvs.x * an;
            o.y = (cvs.y >= 0.f) ? cvs.y * am : cvs.y * an;
            o.z = (cvs.z >= 0.f) ? cvs.z * am : cvs.z * an;
            o.w = (cvs.w >= 0.f) ? cvs.w * am : cvs.w * an;
            *(float4*)&orow[(it * 4 + rr) * D + lane * 4] = o;  // 1KB/wave contiguous
        }
    }
}

// ---------------------------------------------------------------------------
extern "C" void kernel_launch(void* const* d_in, const int* in_sizes, int n_in,
                              void* d_out, int out_size, void* d_ws, size_t ws_size,
                              hipStream_t stream) {
    const float* q  = (const float*)d_in[0];
    // d_in[1] (k) and d_in[4] (k_weights) are provably unused: softmax over s sums to 1.
    const float* v  = (const float*)d_in[2];
    const float* qw = (const float*)d_in[3];
    const float* vw = (const float*)d_in[5];
    float* out = (float*)d_out;
    float* ws  = (float*)d_ws;

    kA<<<B * NT + 256, 256, 0, stream>>>(q, v, qw, vw, ws);
    kB<<<34, 256, 0, stream>>>(ws);
    kC<<<1024, 256, 0, stream>>>(q, ws);
    kE<<<B * NE, 256, 0, stream>>>(q, ws, out);
}

// Round 7
// 71.249 us; speedup vs baseline: 1.3670x; 1.3670x over previous
//
#include <hip/hip_runtime.h>

// Problem constants
#define B 4
#define S 8192
#define D 256
#define H 8
#define NT 128               // col-stat tiles per batch (kA), 64 rows each
#define LOG2E 1.4426950408889634f

// Workspace layout (float offsets)
#define WS_WQ    0
#define WS_WV    8
#define WS_QMAX  16
#define WS_QMIN  (WS_QMAX + B*D)
#define WS_CV    (WS_QMIN + B*D)
#define WS_ZACC  (WS_CV + B*D)          // B*H*D = 8192 accumulators
#define WS_WP    (WS_ZACC + B*H*D)      // 1024 weight partials
#define WS_P1    (WS_WP + 1024)
#define WS_P2    (WS_P1 + B*NT*D)
#define WS_P3    (WS_P2 + B*NT*D)

// ---------------------------------------------------------------------------
// kA: blocks [0,512): per-tile col stats of q (max/min) and v (sum).
//     blocks [512,768): weight-chunk partial sums.
__global__ __launch_bounds__(256) void kA(const float* __restrict__ q,
                                          const float* __restrict__ v,
                                          const float* __restrict__ qw,
                                          const float* __restrict__ vw,
                                          float* __restrict__ ws) {
    const int blk = blockIdx.x;
    const int t = threadIdx.x, w = t >> 6, lane = t & 63;

    if (blk >= B * NT) {                       // weight partials
        const int i = blk - B * NT;            // 0..255: which=i>>7, h=(i>>4)&7, ch=i&15
        const float4* src = (const float4*)(((i >> 7) ? vw : qw)
                              + (size_t)((i >> 4) & 7) * D * D) + (i & 15) * 1024;
        float sm = 0.f;
        #pragma unroll
        for (int j = 0; j < 4; ++j) {
            float4 a4 = src[j * 256 + t];
            sm += (a4.x + a4.y) + (a4.z + a4.w);
        }
        #pragma unroll
        for (int off = 32; off; off >>= 1) sm += __shfl_down(sm, off, 64);
        if (lane == 0) ws[WS_WP + i * 4 + w] = sm;
        return;
    }

    const int b = blk >> 7, tl = blk & (NT - 1);
    const int g = lane >> 4, cl = lane & 15;
    const int cblk = w * 16 + cl;              // 16B col block, 0..63
    const float4* qbase = (const float4*)(q + ((size_t)b * S + tl * 64) * D);
    const float4* vbase = (const float4*)(v + ((size_t)b * S + tl * 64) * D);
    float4 qmx = make_float4(-3.4e38f, -3.4e38f, -3.4e38f, -3.4e38f);
    float4 qmn = make_float4(3.4e38f, 3.4e38f, 3.4e38f, 3.4e38f);
    float4 vs = make_float4(0.f, 0.f, 0.f, 0.f);
    #pragma unroll 4
    for (int i = 0; i < 16; ++i) {
        const int row = i * 4 + g;
        float4 a4 = qbase[row * 64 + cblk];
        qmx.x = fmaxf(qmx.x, a4.x); qmx.y = fmaxf(qmx.y, a4.y);
        qmx.z = fmaxf(qmx.z, a4.z); qmx.w = fmaxf(qmx.w, a4.w);
        qmn.x = fminf(qmn.x, a4.x); qmn.y = fminf(qmn.y, a4.y);
        qmn.z = fminf(qmn.z, a4.z); qmn.w = fminf(qmn.w, a4.w);
        float4 b4 = vbase[row * 64 + cblk];
        vs.x += b4.x; vs.y += b4.y; vs.z += b4.z; vs.w += b4.w;
    }
    #pragma unroll
    for (int off = 16; off <= 32; off <<= 1) {
        qmx.x = fmaxf(qmx.x, __shfl_xor(qmx.x, off, 64));
        qmx.y = fmaxf(qmx.y, __shfl_xor(qmx.y, off, 64));
        qmx.z = fmaxf(qmx.z, __shfl_xor(qmx.z, off, 64));
        qmx.w = fmaxf(qmx.w, __shfl_xor(qmx.w, off, 64));
        qmn.x = fminf(qmn.x, __shfl_xor(qmn.x, off, 64));
        qmn.y = fminf(qmn.y, __shfl_xor(qmn.y, off, 64));
        qmn.z = fminf(qmn.z, __shfl_xor(qmn.z, off, 64));
        qmn.w = fminf(qmn.w, __shfl_xor(qmn.w, off, 64));
        vs.x += __shfl_xor(vs.x, off, 64);
        vs.y += __shfl_xor(vs.y, off, 64);
        vs.z += __shfl_xor(vs.z, off, 64);
        vs.w += __shfl_xor(vs.w, off, 64);
    }
    if (g == 0) {
        size_t pi = (size_t)(b * NT + tl) * D + cblk * 4;
        *(float4*)&ws[WS_P1 + pi] = qmx;
        *(float4*)&ws[WS_P2 + pi] = qmn;
        *(float4*)&ws[WS_P3 + pi] = vs;
    }
}

// ---------------------------------------------------------------------------
// kB: blocks 0..31 finish col stats; block 32 finishes weight sums;
//     block 33 zeroes the Z accumulators.
__global__ __launch_bounds__(256) void kB(float* __restrict__ ws) {
    const int blk = blockIdx.x, t = threadIdx.x;
    if (blk < 32) {
        const int bb = blk >> 3, oct = blk & 7;
        const int dl = t >> 3, sub = t & 7;
        const int d = oct * 32 + dl;
        float mx = -3.4e38f, mn = 3.4e38f, sm = 0.f;
        #pragma unroll 4
        for (int i = 0; i < 16; ++i) {
            size_t idx = (size_t)(bb * NT + sub * 16 + i) * D + d;
            mx = fmaxf(mx, ws[WS_P1 + idx]);
            mn = fminf(mn, ws[WS_P2 + idx]);
            sm += ws[WS_P3 + idx];
        }
        #pragma unroll
        for (int off = 1; off < 8; off <<= 1) {
            mx = fmaxf(mx, __shfl_xor(mx, off, 64));
            mn = fminf(mn, __shfl_xor(mn, off, 64));
            sm += __shfl_xor(sm, off, 64);
        }
        if (sub == 0) {
            ws[WS_QMAX + bb * D + d] = mx;
            ws[WS_QMIN + bb * D + d] = mn;
            ws[WS_CV + bb * D + d] = sm * (float)D;
        }
    } else if (blk == 32) {
        const int o = t >> 4, j = t & 15;        // o: 0..15 = (which,h)
        float s = 0.f;
        #pragma unroll
        for (int ww = 0; ww < 4; ++ww) s += ws[WS_WP + (o * 16 + j) * 4 + ww];
        #pragma unroll
        for (int off = 1; off < 16; off <<= 1) s += __shfl_xor(s, off, 64);
        if (j == 0) ws[(o >= 8) ? (WS_WV + o - 8) : (WS_WQ + o)] = s;
    } else {
        #pragma unroll
        for (int e = 0; e < 8; ++e)
            *(float4*)&ws[WS_ZACC + e * 1024 + t * 4] = make_float4(0.f, 0.f, 0.f, 0.f);
    }
}

// ---------------------------------------------------------------------------
// kC: Z partials over 32-row chunks, accumulated with atomicAdd into WS_ZACC.
__global__ __launch_bounds__(256) void kC(const float* __restrict__ q,
                                          float* __restrict__ ws) {
    const int blk = blockIdx.x;          // 1024 blocks: b = blk>>8, chunk = blk&255
    const int b = blk >> 8, c = blk & 255;
    const int d = threadIdx.x;
    const float qmx = ws[WS_QMAX + b * D + d];
    const float qmn = ws[WS_QMIN + b * D + d];
    float a[H], cc[H], z[H];
    #pragma unroll
    for (int h = 0; h < H; ++h) {
        float wq_ = ws[WS_WQ + h];
        float M = (wq_ >= 0.f) ? wq_ * qmx : wq_ * qmn;  // max_s of wq*q[b,s,d]
        a[h] = wq_ * LOG2E;
        cc[h] = -M * LOG2E;
        z[h] = 0.f;
    }
    const float* qp = q + ((size_t)b * S + c * 32) * D + d;
    #pragma unroll 4
    for (int r = 0; r < 32; ++r) {
        float qv = qp[(size_t)r * D];
        #pragma unroll
        for (int h = 0; h < H; ++h) z[h] += exp2f(fmaf(qv, a[h], cc[h]));
    }
    #pragma unroll
    for (int h = 0; h < H; ++h)
        atomicAdd(&ws[WS_ZACC + (b * H + h) * D + d], z[h]);
}

// ---------------------------------------------------------------------------
// kE v4: lane-per-row, heads split across waves. 512 blocks x 64 rows.
// Wave w computes heads {2w, 2w+1} for all 64 rows (lane l = row l).
// q staged per 32-col chunk in [64][33] LDS (2-way banks, free); chunk c+1
// register-prefetched during compute of chunk c. kc in LDS, wave-uniform
// broadcast reads. No cross-lane ops in the main loop. Output via per-row
// head-reduce in LDS, then wave-contiguous 1KB float4 stores.
__global__ __launch_bounds__(256) void kE(const float* __restrict__ q,
                                          const float* __restrict__ ws,
                                          float* __restrict__ out) {
    __shared__ float kcs[H * D];          // 8 KB  [h][d]
    __shared__ float tile[64 * 33];       // 8.4 KB, +1-padded 32-col chunk
    __shared__ float abuf[64 * 10];       // per-row A[h] (padded)
    __shared__ float ab2[64 * 2];         // per-row amax/amin

    const int blk = blockIdx.x;           // 512 = B * 128
    const int b = blk >> 7, tl = blk & 127;
    const int t = threadIdx.x, w = t >> 6, l = t & 63;
    const int row0 = tl * 64;

    // staging pattern: thread t covers rows {t>>3, 32+(t>>3)}, cols 4*(t&7)..
    const int srow = t >> 3, scb = 4 * (t & 7);
    const float* qg = q + ((size_t)b * S + row0) * D;
    float4 rA = *(const float4*)(qg + (size_t)srow * D + scb);
    float4 rB = *(const float4*)(qg + (size_t)(srow + 32) * D + scb);

    // kc prologue (overlaps the loads above): kc[h][d] = -M*log2e - log2(Z)
    #pragma unroll
    for (int e = 0; e < 8; ++e) {
        const int idx = e * 256 + t;
        const int h = idx >> 8, d = idx & 255;
        const float wq_ = ws[WS_WQ + h];
        const float M = (wq_ >= 0.f) ? wq_ * ws[WS_QMAX + b * D + d]
                                     : wq_ * ws[WS_QMIN + b * D + d];
        kcs[idx] = -M * LOG2E - log2f(ws[WS_ZACC + (b * H + h) * D + d]);
    }

    const int h0 = 2 * w;
    const float a0 = ws[WS_WQ + h0] * LOG2E;
    const float a1 = ws[WS_WQ + h0 + 1] * LOG2E;
    const float wv0 = ws[WS_WV + h0];
    const float wv1 = ws[WS_WV + h0 + 1];

    float acc0 = 0.f, acc1 = 0.f;

    for (int c = 0; c < 8; ++c) {
        *(float4*)&tile[srow * 33 + scb] = rA;
        *(float4*)&tile[(srow + 32) * 33 + scb] = rB;
        __syncthreads();
        if (c < 7) {   // prefetch next chunk; latency hides under compute
            rA = *(const float4*)(qg + (size_t)srow * D + 32 * (c + 1) + scb);
            rB = *(const float4*)(qg + (size_t)(srow + 32) * D + 32 * (c + 1) + scb);
        }
        const float* kc0 = &kcs[h0 * D + 32 * c];
        const float* kc1 = &kcs[(h0 + 1) * D + 32 * c];
        #pragma unroll
        for (int j = 0; j < 8; ++j) {
            const float4 qv = *(const float4*)&tile[l * 33 + 4 * j];  // 2-way, free
            const float4 k0 = *(const float4*)&kc0[4 * j];            // uniform bcast
            const float4 k1 = *(const float4*)&kc1[4 * j];
            acc0 += (exp2f(fmaf(qv.x, a0, k0.x)) + exp2f(fmaf(qv.y, a0, k0.y)))
                  + (exp2f(fmaf(qv.z, a0, k0.z)) + exp2f(fmaf(qv.w, a0, k0.w)));
            acc1 += (exp2f(fmaf(qv.x, a1, k1.x)) + exp2f(fmaf(qv.y, a1, k1.y)))
                  + (exp2f(fmaf(qv.z, a1, k1.z)) + exp2f(fmaf(qv.w, a1, k1.w)));
        }
        __syncthreads();
    }

    // per-row head values -> reduce max/min over h
    abuf[l * 10 + h0]     = wv0 * acc0;
    abuf[l * 10 + h0 + 1] = wv1 * acc1;
    __syncthreads();
    if (w == 0) {
        float mx = -3.4e38f, mn = 3.4e38f;
        #pragma unroll
        for (int k = 0; k < 8; ++k) {
            const float A = abuf[l * 10 + k];
            mx = fmaxf(mx, A);
            mn = fminf(mn, A);
        }
        ab2[l * 2] = mx;
        ab2[l * 2 + 1] = mn;
    }
    __syncthreads();

    // output: wave w writes rows w*16 .. w*16+15, 1KB contiguous per store
    const float4 cv4 = *(const float4*)&ws[WS_CV + b * D + l * 4];
    float* og = out + ((size_t)b * S + row0 + w * 16) * D;
    #pragma unroll
    for (int rr = 0; rr < 16; ++rr) {
        const float am = ab2[(w * 16 + rr) * 2];      // uniform bcast
        const float an = ab2[(w * 16 + rr) * 2 + 1];
        float4 o;
        o.x = (cv4.x >= 0.f) ? cv4.x * am : cv4.x * an;
        o.y = (cv4.y >= 0.f) ? cv4.y * am : cv4.y * an;
        o.z = (cv4.z >= 0.f) ? cv4.z * am : cv4.z * an;
        o.w = (cv4.w >= 0.f) ? cv4.w * am : cv4.w * an;
        *(float4*)&og[(size_t)rr * D + l * 4] = o;
    }
}

// ---------------------------------------------------------------------------
extern "C" void kernel_launch(void* const* d_in, const int* in_sizes, int n_in,
                              void* d_out, int out_size, void* d_ws, size_t ws_size,
                              hipStream_t stream) {
    const float* q  = (const float*)d_in[0];
    // d_in[1] (k) and d_in[4] (k_weights) are provably unused: softmax over s sums to 1.
    const float* v  = (const float*)d_in[2];
    const float* qw = (const float*)d_in[3];
    const float* vw = (const float*)d_in[5];
    float* out = (float*)d_out;
    float* ws  = (float*)d_ws;

    kA<<<B * NT + 256, 256, 0, stream>>>(q, v, qw, vw, ws);
    kB<<<34, 256, 0, stream>>>(ws);
    kC<<<1024, 256, 0, stream>>>(q, ws);
    kE<<<B * 128, 256, 0, stream>>>(q, ws, out);
}

// Round 8
// 61.244 us; speedup vs baseline: 1.5904x; 1.1634x over previous
//
#include <hip/hip_runtime.h>

// Problem constants
#define B 4
#define S 8192
#define D 256
#define H 8
#define NT 128               // col-stat tiles per batch (kA), 64 rows each
#define LOG2E 1.4426950408889634f
#define E2(x) __builtin_amdgcn_exp2f(x)

// Workspace layout (float offsets)
#define WS_WQ    0
#define WS_WV    8
#define WS_QMAX  16
#define WS_QMIN  (WS_QMAX + B*D)
#define WS_CV    (WS_QMIN + B*D)
#define WS_ZACC  (WS_CV + B*D)          // B*H*D
#define WS_KC    (WS_ZACC + B*H*D)      // B*H*D
#define WS_WP    (WS_KC + B*H*D)        // 1024 weight partials
#define WS_P1    (WS_WP + 1024)
#define WS_P2    (WS_P1 + B*NT*D)
#define WS_P3    (WS_P2 + B*NT*D)

// ---------------------------------------------------------------------------
// kA: blocks [0,512): per-tile col stats of q (max/min) and v (sum).
//     blocks [512,768): weight-chunk partial sums.
__global__ __launch_bounds__(256) void kA(const float* __restrict__ q,
                                          const float* __restrict__ v,
                                          const float* __restrict__ qw,
                                          const float* __restrict__ vw,
                                          float* __restrict__ ws) {
    const int blk = blockIdx.x;
    const int t = threadIdx.x, w = t >> 6, lane = t & 63;

    if (blk >= B * NT) {                       // weight partials
        const int i = blk - B * NT;            // 0..255: which=i>>7, h=(i>>4)&7, ch=i&15
        const float4* src = (const float4*)(((i >> 7) ? vw : qw)
                              + (size_t)((i >> 4) & 7) * D * D) + (i & 15) * 1024;
        float sm = 0.f;
        #pragma unroll
        for (int j = 0; j < 4; ++j) {
            float4 a4 = src[j * 256 + t];
            sm += (a4.x + a4.y) + (a4.z + a4.w);
        }
        #pragma unroll
        for (int off = 32; off; off >>= 1) sm += __shfl_down(sm, off, 64);
        if (lane == 0) ws[WS_WP + i * 4 + w] = sm;
        return;
    }

    const int b = blk >> 7, tl = blk & (NT - 1);
    const int g = lane >> 4, cl = lane & 15;
    const int cblk = w * 16 + cl;              // 16B col block, 0..63
    const float4* qbase = (const float4*)(q + ((size_t)b * S + tl * 64) * D);
    const float4* vbase = (const float4*)(v + ((size_t)b * S + tl * 64) * D);
    float4 qmx = make_float4(-3.4e38f, -3.4e38f, -3.4e38f, -3.4e38f);
    float4 qmn = make_float4(3.4e38f, 3.4e38f, 3.4e38f, 3.4e38f);
    float4 vs = make_float4(0.f, 0.f, 0.f, 0.f);
    #pragma unroll 4
    for (int i = 0; i < 16; ++i) {
        const int row = i * 4 + g;
        float4 a4 = qbase[row * 64 + cblk];
        qmx.x = fmaxf(qmx.x, a4.x); qmx.y = fmaxf(qmx.y, a4.y);
        qmx.z = fmaxf(qmx.z, a4.z); qmx.w = fmaxf(qmx.w, a4.w);
        qmn.x = fminf(qmn.x, a4.x); qmn.y = fminf(qmn.y, a4.y);
        qmn.z = fminf(qmn.z, a4.z); qmn.w = fminf(qmn.w, a4.w);
        float4 b4 = vbase[row * 64 + cblk];
        vs.x += b4.x; vs.y += b4.y; vs.z += b4.z; vs.w += b4.w;
    }
    #pragma unroll
    for (int off = 16; off <= 32; off <<= 1) {
        qmx.x = fmaxf(qmx.x, __shfl_xor(qmx.x, off, 64));
        qmx.y = fmaxf(qmx.y, __shfl_xor(qmx.y, off, 64));
        qmx.z = fmaxf(qmx.z, __shfl_xor(qmx.z, off, 64));
        qmx.w = fmaxf(qmx.w, __shfl_xor(qmx.w, off, 64));
        qmn.x = fminf(qmn.x, __shfl_xor(qmn.x, off, 64));
        qmn.y = fminf(qmn.y, __shfl_xor(qmn.y, off, 64));
        qmn.z = fminf(qmn.z, __shfl_xor(qmn.z, off, 64));
        qmn.w = fminf(qmn.w, __shfl_xor(qmn.w, off, 64));
        vs.x += __shfl_xor(vs.x, off, 64);
        vs.y += __shfl_xor(vs.y, off, 64);
        vs.z += __shfl_xor(vs.z, off, 64);
        vs.w += __shfl_xor(vs.w, off, 64);
    }
    if (g == 0) {
        size_t pi = (size_t)(b * NT + tl) * D + cblk * 4;
        *(float4*)&ws[WS_P1 + pi] = qmx;
        *(float4*)&ws[WS_P2 + pi] = qmn;
        *(float4*)&ws[WS_P3 + pi] = vs;
    }
}

// ---------------------------------------------------------------------------
// kB: blocks 0..31 finish col stats; block 32 finishes weight sums;
//     block 33 zeroes the Z accumulators.
__global__ __launch_bounds__(256) void kB(float* __restrict__ ws) {
    const int blk = blockIdx.x, t = threadIdx.x;
    if (blk < 32) {
        const int bb = blk >> 3, oct = blk & 7;
        const int dl = t >> 3, sub = t & 7;
        const int d = oct * 32 + dl;
        float mx = -3.4e38f, mn = 3.4e38f, sm = 0.f;
        #pragma unroll 4
        for (int i = 0; i < 16; ++i) {
            size_t idx = (size_t)(bb * NT + sub * 16 + i) * D + d;
            mx = fmaxf(mx, ws[WS_P1 + idx]);
            mn = fminf(mn, ws[WS_P2 + idx]);
            sm += ws[WS_P3 + idx];
        }
        #pragma unroll
        for (int off = 1; off < 8; off <<= 1) {
            mx = fmaxf(mx, __shfl_xor(mx, off, 64));
            mn = fminf(mn, __shfl_xor(mn, off, 64));
            sm += __shfl_xor(sm, off, 64);
        }
        if (sub == 0) {
            ws[WS_QMAX + bb * D + d] = mx;
            ws[WS_QMIN + bb * D + d] = mn;
            ws[WS_CV + bb * D + d] = sm * (float)D;
        }
    } else if (blk == 32) {
        const int o = t >> 4, j = t & 15;        // o: 0..15 = (which,h)
        float s = 0.f;
        #pragma unroll
        for (int ww = 0; ww < 4; ++ww) s += ws[WS_WP + (o * 16 + j) * 4 + ww];
        #pragma unroll
        for (int off = 1; off < 16; off <<= 1) s += __shfl_xor(s, off, 64);
        if (j == 0) ws[(o >= 8) ? (WS_WV + o - 8) : (WS_WQ + o)] = s;
    } else {
        #pragma unroll
        for (int e = 0; e < 8; ++e)
            *(float4*)&ws[WS_ZACC + e * 1024 + t * 4] = make_float4(0.f, 0.f, 0.f, 0.f);
    }
}

// ---------------------------------------------------------------------------
// kC: Z partials over 32-row chunks, accumulated with atomicAdd into WS_ZACC.
__global__ __launch_bounds__(256) void kC(const float* __restrict__ q,
                                          float* __restrict__ ws) {
    const int blk = blockIdx.x;          // 1024 blocks: b = blk>>8, chunk = blk&255
    const int b = blk >> 8, c = blk & 255;
    const int d = threadIdx.x;
    const float qmx = ws[WS_QMAX + b * D + d];
    const float qmn = ws[WS_QMIN + b * D + d];
    float a[H], cc[H], z[H];
    #pragma unroll
    for (int h = 0; h < H; ++h) {
        float wq_ = ws[WS_WQ + h];
        float M = (wq_ >= 0.f) ? wq_ * qmx : wq_ * qmn;  // max_s of wq*q[b,s,d]
        a[h] = wq_ * LOG2E;
        cc[h] = -M * LOG2E;
        z[h] = 0.f;
    }
    const float* qp = q + ((size_t)b * S + c * 32) * D + d;
    #pragma unroll 4
    for (int r = 0; r < 32; ++r) {
        float qv = qp[(size_t)r * D];
        #pragma unroll
        for (int h = 0; h < H; ++h) z[h] += E2(fmaf(qv, a[h], cc[h]));
    }
    #pragma unroll
    for (int h = 0; h < H; ++h)
        atomicAdd(&ws[WS_ZACC + (b * H + h) * D + d], z[h]);
}

// ---------------------------------------------------------------------------
// kD: kc[b,h,d] = -M'[h,d] - log2(Z[b,h,d]). 32 blocks, trivial.
__global__ __launch_bounds__(256) void kD(float* __restrict__ ws) {
    const int b = blockIdx.x >> 3, h = blockIdx.x & 7;
    const int d = threadIdx.x;
    const float wq_ = ws[WS_WQ + h];
    const float M = (wq_ >= 0.f) ? wq_ * ws[WS_QMAX + b * D + d]
                                 : wq_ * ws[WS_QMIN + b * D + d];
    ws[WS_KC + (b * H + h) * D + d] =
        -M * LOG2E - __builtin_amdgcn_logf(ws[WS_ZACC + (b * H + h) * D + d]);
}

// ---------------------------------------------------------------------------
// kE v5: 2048 blocks x 16 rows (8 blocks/CU). Thread = (row r = t>>4,
// slice = t&15): 16 cols of one row, all 8 heads. q read straight from
// global (1KB-contiguous per 16 lanes), no staging, no main-loop barriers.
// kc in LDS once per block, swizzled [h][j][slice] so float4 reads are
// 16B-aligned and conflict-free. 4-step shfl_xor(16) reduce; wave-contiguous
// 1KB stores.
__global__ __launch_bounds__(256) void kE(const float* __restrict__ q,
                                          const float* __restrict__ ws,
                                          float* __restrict__ out) {
    __shared__ float kcs[H * D];          // [h][j][slice][c] = h*256+j*64+slice*4+c
    __shared__ float ab2[16 * 2];

    const int blk = blockIdx.x;           // 2048 = B * 512
    const int b = blk >> 9, tl = blk & 511;
    const int t = threadIdx.x, w = t >> 6, lane = t & 63;
    const int r = t >> 4, slice = t & 15;

    // issue q loads first; HBM latency hides under the kc prologue
    const float4* qp = (const float4*)(q + ((size_t)b * S + tl * 16 + r) * D
                                       + slice * 16);
    const float4 q0 = qp[0], q1 = qp[1], q2 = qp[2], q3 = qp[3];

    // kc -> swizzled LDS (d = t: slice=d>>4, j=(d>>2)&3, c=d&3)
    const int dst = ((t >> 2) & 3) * 64 + (t >> 4) * 4 + (t & 3);
    #pragma unroll
    for (int h = 0; h < H; ++h)
        kcs[h * 256 + dst] = ws[WS_KC + (b * H + h) * D + t];

    float a[H], wv_[H];
    #pragma unroll
    for (int h = 0; h < H; ++h) {
        a[h] = ws[WS_WQ + h] * LOG2E;
        wv_[h] = ws[WS_WV + h];
    }
    const float4 cv4 = *(const float4*)&ws[WS_CV + b * D + lane * 4];
    __syncthreads();

    float p[H];
    #pragma unroll
    for (int h = 0; h < H; ++h) p[h] = 0.f;

    const float4* kc4 = (const float4*)kcs;
    #pragma unroll
    for (int j = 0; j < 4; ++j) {
        const float4 qv = (j == 0) ? q0 : (j == 1) ? q1 : (j == 2) ? q2 : q3;
        #pragma unroll
        for (int h = 0; h < H; ++h) {
            const float4 k = kc4[h * 64 + j * 16 + slice];
            p[h] += (E2(fmaf(qv.x, a[h], k.x)) + E2(fmaf(qv.y, a[h], k.y)))
                  + (E2(fmaf(qv.z, a[h], k.z)) + E2(fmaf(qv.w, a[h], k.w)));
        }
    }
    #pragma unroll
    for (int st = 1; st < 16; st <<= 1) {
        #pragma unroll
        for (int h = 0; h < H; ++h) p[h] += __shfl_xor(p[h], st, 16);
    }
    float amax = -3.4e38f, amin = 3.4e38f;
    #pragma unroll
    for (int h = 0; h < H; ++h) {
        const float A = wv_[h] * p[h];
        amax = fmaxf(amax, A);
        amin = fminf(amin, A);
    }
    if (slice == 0) {
        ab2[r * 2] = amax;
        ab2[r * 2 + 1] = amin;
    }
    __syncthreads();

    float* og = out + ((size_t)b * S + tl * 16 + w * 4) * D;
    #pragma unroll
    for (int rr = 0; rr < 4; ++rr) {
        const float am = ab2[(w * 4 + rr) * 2];       // uniform broadcast
        const float an = ab2[(w * 4 + rr) * 2 + 1];
        float4 o;
        o.x = (cv4.x >= 0.f) ? cv4.x * am : cv4.x * an;
        o.y = (cv4.y >= 0.f) ? cv4.y * am : cv4.y * an;
        o.z = (cv4.z >= 0.f) ? cv4.z * am : cv4.z * an;
        o.w = (cv4.w >= 0.f) ? cv4.w * am : cv4.w * an;
        *(float4*)&og[(size_t)rr * D + lane * 4] = o;  // 1KB/wave contiguous
    }
}

// ---------------------------------------------------------------------------
extern "C" void kernel_launch(void* const* d_in, const int* in_sizes, int n_in,
                              void* d_out, int out_size, void* d_ws, size_t ws_size,
                              hipStream_t stream) {
    const float* q  = (const float*)d_in[0];
    // d_in[1] (k) and d_in[4] (k_weights) are provably unused: softmax over s sums to 1.
    const float* v  = (const float*)d_in[2];
    const float* qw = (const float*)d_in[3];
    const float* vw = (const float*)d_in[5];
    float* out = (float*)d_out;
    float* ws  = (float*)d_ws;

    kA<<<B * NT + 256, 256, 0, stream>>>(q, v, qw, vw, ws);
    kB<<<34, 256, 0, stream>>>(ws);
    kC<<<1024, 256, 0, stream>>>(q, ws);
    kD<<<B * H, 256, 0, stream>>>(ws);
    kE<<<B * 512, 256, 0, stream>>>(q, ws, out);
}